// Round 1
// baseline (483.923 us; speedup 1.0000x reference)
//
#include <hip/hip_runtime.h>

#define NN 100000
#define NG 512
#define NCH 128
#define EPSV 0.001f
#define C0 128
#define C1 384
#define C2 1152
#define CT 1664       // C0+C1+C2 components per (node) across all 3 ways
#define V4 416        // CT/4 float4 slots per node
#define NT 256
#define OFF1 12800000L
#define OFF2 51200000L

static __device__ __forceinline__ float4 ld4(const float* __restrict__ p, long i) {
  return *reinterpret_cast<const float4*>(p + i);
}

// ---- graph start offsets (batch is sorted; every graph id present) ----
__global__ void k_offsets(const int* __restrict__ b32, int* __restrict__ start) {
  int g = threadIdx.x;
  // int64 layout: odd int32 words are zero hi-words -> b32[NN-1] (odd index) == 0.
  // int32 layout: last element must be 511 (sorted, all graphs present).
  bool is64 = (b32[NN - 1] == 0);
  if (g < NG) {
    int lo = 0, hi = NN;
    while (lo < hi) {
      int mid = (lo + hi) >> 1;
      int v = is64 ? b32[2 * mid] : b32[mid];
      if (v < g) lo = mid + 1; else hi = mid;
    }
    start[g] = lo;
  }
  if (g == 0) start[NG] = NN;
}

// flat float4 component slot -> source address
static __device__ __forceinline__ float4 load_x4(const float* __restrict__ x0,
    const float* __restrict__ x1, const float* __restrict__ x2, int n, int idx) {
  if (idx < 32)  return ld4(x0, (long)n * C0 + (idx << 2));
  if (idx < 128) return ld4(x1, (long)n * C1 + ((idx - 32) << 2));
  return ld4(x2, (long)n * C2 + ((idx - 128) << 2));
}

static __device__ __forceinline__ void store_x4(float* __restrict__ out, int n, int idx, float4 o) {
  if (idx < 32)       *reinterpret_cast<float4*>(out + (long)n * C0 + (idx << 2)) = o;
  else if (idx < 128) *reinterpret_cast<float4*>(out + OFF1 + (long)n * C1 + ((idx - 32) << 2)) = o;
  else                *reinterpret_cast<float4*>(out + OFF2 + (long)n * C2 + ((idx - 128) << 2)) = o;
}

// ---- pass 1: per-(graph,part) partial sum / sumsq over node sub-range ----
__global__ __launch_bounds__(NT) void k_partial(const float* __restrict__ x0,
    const float* __restrict__ x1, const float* __restrict__ x2,
    const int* __restrict__ start, float* __restrict__ psum,
    float* __restrict__ pssq, int splitb) {
  int g = blockIdx.x / splitb;
  int p = blockIdx.x - g * splitb;
  int t = threadIdx.x;
  int s = start[g], e = start[g + 1];
  int per = (e - s + splitb - 1) / splitb;
  int ns = s + p * per;
  int ne = min(e, ns + per);
  float sa0=0,sa1=0,sa2=0,sa3=0, qa0=0,qa1=0,qa2=0,qa3=0;
  float sb0=0,sb1=0,sb2=0,sb3=0, qb0=0,qb1=0,qb2=0,qb3=0;
  for (int n = ns; n < ne; ++n) {
    float4 v = load_x4(x0, x1, x2, n, t);
    sa0 += v.x; sa1 += v.y; sa2 += v.z; sa3 += v.w;
    qa0 += v.x*v.x; qa1 += v.y*v.y; qa2 += v.z*v.z; qa3 += v.w*v.w;
    if (t < V4 - NT) {
      float4 u = load_x4(x0, x1, x2, n, t + NT);
      sb0 += u.x; sb1 += u.y; sb2 += u.z; sb3 += u.w;
      qb0 += u.x*u.x; qb1 += u.y*u.y; qb2 += u.z*u.z; qb3 += u.w*u.w;
    }
  }
  long base = (long)blockIdx.x * CT;
  *reinterpret_cast<float4*>(psum + base + (t << 2)) = make_float4(sa0, sa1, sa2, sa3);
  *reinterpret_cast<float4*>(pssq + base + (t << 2)) = make_float4(qa0, qa1, qa2, qa3);
  if (t < V4 - NT) {
    *reinterpret_cast<float4*>(psum + base + ((t + NT) << 2)) = make_float4(sb0, sb1, sb2, sb3);
    *reinterpret_cast<float4*>(pssq + base + ((t + NT) << 2)) = make_float4(qb0, qb1, qb2, qb3);
  }
}

// ---- pass 1b: reduce partials, emit A = alpha*mean, B = gamma*rsqrt(var+eps) ----
__global__ __launch_bounds__(NT) void k_finalize(const float* __restrict__ psum,
    const float* __restrict__ pssq, const float* __restrict__ alpha,
    const float* __restrict__ gamma, const float* __restrict__ degree,
    float* __restrict__ A, float* __restrict__ B, int splitb) {
  int g = blockIdx.x;
  int t = threadIdx.x;
  float invd = 1.0f / degree[g];
  for (int c = t; c < CT; c += NT) {
    float s = 0.f, q = 0.f;
    for (int p = 0; p < splitb; ++p) {
      long base = (long)(g * splitb + p) * CT;
      s += psum[base + c];
      q += pssq[base + c];
    }
    int way, ch;
    if (c < C0)          { way = 0; ch = c; }
    else if (c < C0 + C1){ way = 1; ch = (c - C0) / 3; }
    else                 { way = 2; ch = (c - C0 - C1) / 9; }
    float a  = alpha[way * NCH + ch];
    float gm = gamma[way * NCH + ch];
    float m  = s * invd;
    float var = q * invd - m * m * a * (2.0f - a);   // E[(x-a*m)^2]
    A[(long)g * CT + c] = m * a;
    B[(long)g * CT + c] = gm * rsqrtf(var + EPSV);
  }
}

// ---- pass 2: out = (x - A)*B (+beta for way 0) ----
__global__ __launch_bounds__(NT) void k_apply(const float* __restrict__ x0,
    const float* __restrict__ x1, const float* __restrict__ x2,
    const float* __restrict__ beta, const int* __restrict__ start,
    const float* __restrict__ A, const float* __restrict__ B,
    float* __restrict__ out, int split) {
  int g = blockIdx.x / split;
  int p = blockIdx.x - g * split;
  int t = threadIdx.x;
  long ab = (long)g * CT;
  float4 a0 = ld4(A, ab + (t << 2));
  float4 b0 = ld4(B, ab + (t << 2));
  float4 a1 = make_float4(0,0,0,0), b1 = make_float4(0,0,0,0);
  if (t < V4 - NT) { a1 = ld4(A, ab + ((t + NT) << 2)); b1 = ld4(B, ab + ((t + NT) << 2)); }
  float4 be = make_float4(0,0,0,0);
  if (t < 32) be = ld4(beta, t << 2);   // beta only touches comps < 128 (idx < 32)
  int s = start[g], e = start[g + 1];
  int per = (e - s + split - 1) / split;
  int ns = s + p * per;
  int ne = min(e, ns + per);
  for (int n = ns; n < ne; ++n) {
    float4 v = load_x4(x0, x1, x2, n, t);
    float4 o;
    o.x = (v.x - a0.x) * b0.x + be.x;
    o.y = (v.y - a0.y) * b0.y + be.y;
    o.z = (v.z - a0.z) * b0.z + be.z;
    o.w = (v.w - a0.w) * b0.w + be.w;
    store_x4(out, n, t, o);
    if (t < V4 - NT) {
      float4 u = load_x4(x0, x1, x2, n, t + NT);
      float4 o2;
      o2.x = (u.x - a1.x) * b1.x;
      o2.y = (u.y - a1.y) * b1.y;
      o2.z = (u.z - a1.z) * b1.z;
      o2.w = (u.w - a1.w) * b1.w;
      store_x4(out, n, t + NT, o2);
    }
  }
}

extern "C" void kernel_launch(void* const* d_in, const int* in_sizes, int n_in,
                              void* d_out, int out_size, void* d_ws, size_t ws_size,
                              hipStream_t stream) {
  const float* x0    = (const float*)d_in[0];
  const float* x1    = (const float*)d_in[1];
  const float* x2    = (const float*)d_in[2];
  const float* alpha = (const float*)d_in[3];
  const float* beta  = (const float*)d_in[4];
  const float* gamma = (const float*)d_in[5];
  const int*   b32   = (const int*)d_in[6];   // batch: int32 or int64 (detected on device)
  const float* degree= (const float*)d_in[7];
  float* out = (float*)d_out;

  char* ws = (char*)d_ws;
  int* start = (int*)ws;                                   // 513 ints
  size_t off = 4096;
  float* A = (float*)(ws + off); off += (size_t)NG * CT * 4;
  float* B = (float*)(ws + off); off += (size_t)NG * CT * 4;
  int splitb = 8;
  while (splitb > 1 && off + 2ull * NG * splitb * CT * 4 > ws_size) splitb >>= 1;
  float* psum = (float*)(ws + off); off += (size_t)NG * splitb * CT * 4;
  float* pssq = (float*)(ws + off);

  k_offsets<<<1, 512, 0, stream>>>(b32, start);
  k_partial<<<NG * splitb, NT, 0, stream>>>(x0, x1, x2, start, psum, pssq, splitb);
  k_finalize<<<NG, NT, 0, stream>>>(psum, pssq, alpha, gamma, degree, A, B, splitb);
  const int split = 8;
  k_apply<<<NG * split, NT, 0, stream>>>(x0, x1, x2, beta, start, A, B, out, split);
}

// Round 2
// 321.167 us; speedup vs baseline: 1.5068x; 1.5068x over previous
//
#include <hip/hip_runtime.h>

#define NN 100000
#define NG 512
#define NCH 128
#define EPSV 0.001f
#define NCHUNK 26        // 2 (x0) + 6 (x1) + 18 (x2) chunks of 16 float4 slots
#define NT 256
#define OFF1 12800000L
#define OFF2 51200000L

// ---- graph start offsets (batch sorted; every graph id present) ----
__global__ void k_offsets(const int* __restrict__ b32, int* __restrict__ start) {
  int g = threadIdx.x;
  // int64 layout: odd int32 words are zero hi-words -> b32[NN-1] (odd index) == 0.
  bool is64 = (b32[NN - 1] == 0);
  if (g < NG) {
    int lo = 0, hi = NN;
    while (lo < hi) {
      int mid = (lo + hi) >> 1;
      int v = is64 ? b32[2 * mid] : b32[mid];
      if (v < g) lo = mid + 1; else hi = mid;
    }
    start[g] = lo;
  }
  if (g == 0) start[NG] = NN;
}

// ---- fused: one block owns (graph g, 16-slot component chunk k) ----
// pass 1: accumulate sum/ssq over all nodes of g (registers)
// reduce: shuffle over node-phases within wave, 2KB LDS across 4 waves
// pass 2: re-read (L2/L3-hot) and write normalized output
__global__ __launch_bounds__(NT) void k_fused(
    const float* __restrict__ x0, const float* __restrict__ x1,
    const float* __restrict__ x2, const float* __restrict__ alpha,
    const float* __restrict__ beta, const float* __restrict__ gamma,
    const int* __restrict__ start, float* __restrict__ out) {
  int bid = blockIdx.x;
  int g = bid / NCHUNK;
  int k = bid - g * NCHUNK;

  const float* src; float* dst; int stride, cbase;
  if (k < 2)      { src = x0; dst = out;        stride = 128;  cbase = k * 64; }
  else if (k < 8) { src = x1; dst = out + OFF1; stride = 384;  cbase = (k - 2) * 64; }
  else            { src = x2; dst = out + OFF2; stride = 1152; cbase = (k - 8) * 64; }
  // global component index of this chunk's first element:
  int gcomp0 = (k < 2) ? cbase : (k < 8) ? 128 + cbase : 512 + cbase;

  int t  = threadIdx.x;
  int s  = t & 15;          // float4 slot within chunk (0..15)
  int ph = t >> 4;          // node phase (0..15)
  int ns = start[g], ne = start[g + 1];
  float invd = 1.0f / (float)(ne - ns);

  long coloff = (long)cbase + (s << 2);

  // ---- pass 1: per-thread accumulate over strided nodes ----
  float s0=0,s1=0,s2=0,s3=0, q0=0,q1=0,q2=0,q3=0;
  #pragma unroll 2
  for (int n = ns + ph; n < ne; n += 16) {
    float4 v = *reinterpret_cast<const float4*>(src + (long)n * stride + coloff);
    s0 += v.x; s1 += v.y; s2 += v.z; s3 += v.w;
    q0 += v.x*v.x; q1 += v.y*v.y; q2 += v.z*v.z; q3 += v.w*v.w;
  }

  // ---- reduce over phases: lanes ^16,^32 within wave, then LDS across waves ----
  #define RED2(v) { v += __shfl_xor(v, 16); v += __shfl_xor(v, 32); }
  RED2(s0) RED2(s1) RED2(s2) RED2(s3) RED2(q0) RED2(q1) RED2(q2) RED2(q3)
  #undef RED2

  __shared__ float red[4][16][8];
  int w = t >> 6, l = t & 63;
  if (l < 16) {
    red[w][l][0]=s0; red[w][l][1]=s1; red[w][l][2]=s2; red[w][l][3]=s3;
    red[w][l][4]=q0; red[w][l][5]=q1; red[w][l][6]=q2; red[w][l][7]=q3;
  }
  __syncthreads();

  float S[4], Q[4];
  #pragma unroll
  for (int j = 0; j < 4; ++j) {
    S[j] = red[0][s][j]   + red[1][s][j]   + red[2][s][j]   + red[3][s][j];
    Q[j] = red[0][s][j+4] + red[1][s][j+4] + red[2][s][j+4] + red[3][s][j+4];
  }

  // ---- per-component A = alpha*mean, B = gamma*rsqrt(var+eps), beta ----
  float A[4], Bv[4], Be[4];
  #pragma unroll
  for (int j = 0; j < 4; ++j) {
    int c = gcomp0 + (s << 2) + j;
    int way, ch;
    if (c < 128)      { way = 0; ch = c; }
    else if (c < 512) { way = 1; ch = (c - 128) / 3; }
    else              { way = 2; ch = (c - 512) / 9; }
    float a  = alpha[way * NCH + ch];
    float gm = gamma[way * NCH + ch];
    float m  = S[j] * invd;
    float var = Q[j] * invd - m * m * a * (2.0f - a);  // E[(x - a*m)^2]
    A[j]  = m * a;
    Bv[j] = gm * rsqrtf(var + EPSV);
    Be[j] = (c < 128) ? beta[c] : 0.0f;
  }

  // ---- pass 2: re-read (cache-hot) and write ----
  #pragma unroll 2
  for (int n = ns + ph; n < ne; n += 16) {
    float4 v = *reinterpret_cast<const float4*>(src + (long)n * stride + coloff);
    float4 o;
    o.x = (v.x - A[0]) * Bv[0] + Be[0];
    o.y = (v.y - A[1]) * Bv[1] + Be[1];
    o.z = (v.z - A[2]) * Bv[2] + Be[2];
    o.w = (v.w - A[3]) * Bv[3] + Be[3];
    *reinterpret_cast<float4*>(dst + (long)n * stride + coloff) = o;
  }
}

extern "C" void kernel_launch(void* const* d_in, const int* in_sizes, int n_in,
                              void* d_out, int out_size, void* d_ws, size_t ws_size,
                              hipStream_t stream) {
  const float* x0    = (const float*)d_in[0];
  const float* x1    = (const float*)d_in[1];
  const float* x2    = (const float*)d_in[2];
  const float* alpha = (const float*)d_in[3];
  const float* beta  = (const float*)d_in[4];
  const float* gamma = (const float*)d_in[5];
  const int*   b32   = (const int*)d_in[6];   // batch: int32 or int64 (device-detected)
  float* out = (float*)d_out;

  int* start = (int*)d_ws;  // 513 ints

  k_offsets<<<1, 512, 0, stream>>>(b32, start);
  k_fused<<<NG * NCHUNK, NT, 0, stream>>>(x0, x1, x2, alpha, beta, gamma, start, out);
}

// Round 3
// 285.494 us; speedup vs baseline: 1.6950x; 1.1250x over previous
//
#include <hip/hip_runtime.h>

#define NN 100000
#define NG 512
#define NCH 128
#define EPSV 0.001f
#define NCHUNK 52        // 4 (x0) + 12 (x1) + 36 (x2) chunks of 8 float4 slots
#define NT 256
#define RCAP 10          // register-staged nodes per thread: covers 320 nodes/graph
#define OFF1 12800000L
#define OFF2 51200000L

// ---- graph start offsets (batch sorted; every graph id present) ----
__global__ void k_offsets(const int* __restrict__ b32, int* __restrict__ start) {
  int g = threadIdx.x;
  // int64 layout: odd int32 words are zero hi-words -> b32[NN-1] (odd index) == 0.
  bool is64 = (b32[NN - 1] == 0);
  if (g < NG) {
    int lo = 0, hi = NN;
    while (lo < hi) {
      int mid = (lo + hi) >> 1;
      int v = is64 ? b32[2 * mid] : b32[mid];
      if (v < g) lo = mid + 1; else hi = mid;
    }
    start[g] = lo;
  }
  if (g == 0) start[NG] = NN;
}

// ---- fused, register-staged: block = (graph g, 8-slot chunk k) ----
__global__ __launch_bounds__(NT) void k_fused(
    const float* __restrict__ x0, const float* __restrict__ x1,
    const float* __restrict__ x2, const float* __restrict__ alpha,
    const float* __restrict__ beta, const float* __restrict__ gamma,
    const int* __restrict__ start, float* __restrict__ out) {
  int bid = blockIdx.x;
  int g = bid / NCHUNK;
  int k = bid - g * NCHUNK;

  const float* src; float* dst; int stride, cbase, gcomp0;
  if (k < 4)       { src = x0; dst = out;        stride = 128;  cbase = k * 32;      gcomp0 = cbase; }
  else if (k < 16) { src = x1; dst = out + OFF1; stride = 384;  cbase = (k-4) * 32;  gcomp0 = 128 + cbase; }
  else             { src = x2; dst = out + OFF2; stride = 1152; cbase = (k-16) * 32; gcomp0 = 512 + cbase; }

  int t  = threadIdx.x;
  int s  = t & 7;           // float4 slot within chunk (0..7)
  int ph = t >> 3;          // node phase (0..31)
  int ns = start[g], ne = start[g + 1];
  float invd = 1.0f / (float)(ne - ns);
  long coloff = (long)cbase + (s << 2);

  // ---- pass 1: load into registers + accumulate ----
  float s0=0,s1=0,s2=0,s3=0, q0=0,q1=0,q2=0,q3=0;
  float4 v[RCAP];
  #pragma unroll
  for (int i = 0; i < RCAP; ++i) {
    int n = ns + ph + (i << 5);
    if (n < ne) {
      float4 u = *reinterpret_cast<const float4*>(src + (long)n * stride + coloff);
      v[i] = u;
      s0 += u.x; s1 += u.y; s2 += u.z; s3 += u.w;
      q0 += u.x*u.x; q1 += u.y*u.y; q2 += u.z*u.z; q3 += u.w*u.w;
    }
  }
  // overflow path (graphs > RCAP*32 nodes): accumulate without staging
  for (int n = ns + ph + (RCAP << 5); n < ne; n += 32) {
    float4 u = *reinterpret_cast<const float4*>(src + (long)n * stride + coloff);
    s0 += u.x; s1 += u.y; s2 += u.z; s3 += u.w;
    q0 += u.x*u.x; q1 += u.y*u.y; q2 += u.z*u.z; q3 += u.w*u.w;
  }

  // ---- reduce over 32 phases: shfl ^8,^16,^32 within wave, LDS across waves ----
  #define RED3(x) { x += __shfl_xor(x, 8); x += __shfl_xor(x, 16); x += __shfl_xor(x, 32); }
  RED3(s0) RED3(s1) RED3(s2) RED3(s3) RED3(q0) RED3(q1) RED3(q2) RED3(q3)
  #undef RED3

  __shared__ float red[4][8][8];
  int w = t >> 6, l = t & 63;
  if (l < 8) {
    red[w][l][0]=s0; red[w][l][1]=s1; red[w][l][2]=s2; red[w][l][3]=s3;
    red[w][l][4]=q0; red[w][l][5]=q1; red[w][l][6]=q2; red[w][l][7]=q3;
  }
  __syncthreads();

  float S[4], Q[4];
  #pragma unroll
  for (int j = 0; j < 4; ++j) {
    S[j] = red[0][s][j]   + red[1][s][j]   + red[2][s][j]   + red[3][s][j];
    Q[j] = red[0][s][j+4] + red[1][s][j+4] + red[2][s][j+4] + red[3][s][j+4];
  }

  // ---- per-component A = alpha*mean, B = gamma*rsqrt(var+eps), beta ----
  float A[4], Bv[4], Be[4];
  #pragma unroll
  for (int j = 0; j < 4; ++j) {
    int c = gcomp0 + (s << 2) + j;
    int way, ch;
    if (c < 128)      { way = 0; ch = c; }
    else if (c < 512) { way = 1; ch = (c - 128) / 3; }
    else              { way = 2; ch = (c - 512) / 9; }
    float a  = alpha[way * NCH + ch];
    float gm = gamma[way * NCH + ch];
    float m  = S[j] * invd;
    float var = Q[j] * invd - m * m * a * (2.0f - a);  // E[(x - a*m)^2]
    A[j]  = m * a;
    Bv[j] = gm * rsqrtf(var + EPSV);
    Be[j] = (c < 128) ? beta[c] : 0.0f;
  }

  // ---- pass 2: apply from registers, stream out ----
  #pragma unroll
  for (int i = 0; i < RCAP; ++i) {
    int n = ns + ph + (i << 5);
    if (n < ne) {
      float4 u = v[i], o;
      o.x = (u.x - A[0]) * Bv[0] + Be[0];
      o.y = (u.y - A[1]) * Bv[1] + Be[1];
      o.z = (u.z - A[2]) * Bv[2] + Be[2];
      o.w = (u.w - A[3]) * Bv[3] + Be[3];
      *reinterpret_cast<float4*>(dst + (long)n * stride + coloff) = o;
    }
  }
  // overflow path: re-read from global (L2-warm), apply, write
  for (int n = ns + ph + (RCAP << 5); n < ne; n += 32) {
    float4 u = *reinterpret_cast<const float4*>(src + (long)n * stride + coloff);
    float4 o;
    o.x = (u.x - A[0]) * Bv[0] + Be[0];
    o.y = (u.y - A[1]) * Bv[1] + Be[1];
    o.z = (u.z - A[2]) * Bv[2] + Be[2];
    o.w = (u.w - A[3]) * Bv[3] + Be[3];
    *reinterpret_cast<float4*>(dst + (long)n * stride + coloff) = o;
  }
}

extern "C" void kernel_launch(void* const* d_in, const int* in_sizes, int n_in,
                              void* d_out, int out_size, void* d_ws, size_t ws_size,
                              hipStream_t stream) {
  const float* x0    = (const float*)d_in[0];
  const float* x1    = (const float*)d_in[1];
  const float* x2    = (const float*)d_in[2];
  const float* alpha = (const float*)d_in[3];
  const float* beta  = (const float*)d_in[4];
  const float* gamma = (const float*)d_in[5];
  const int*   b32   = (const int*)d_in[6];   // batch: int32 or int64 (device-detected)
  float* out = (float*)d_out;

  int* start = (int*)d_ws;  // 513 ints

  k_offsets<<<1, 512, 0, stream>>>(b32, start);
  k_fused<<<NG * NCHUNK, NT, 0, stream>>>(x0, x1, x2, alpha, beta, gamma, start, out);
}

// Round 4
// 242.721 us; speedup vs baseline: 1.9937x; 1.1762x over previous
//
#include <hip/hip_runtime.h>

#define NN 100000
#define NG 512
#define NCH 128
#define EPSV 0.001f
#define NCHUNK 26        // 2 (x0) + 6 (x1) + 18 (x2) chunks of 16 float4 slots
#define NT 256
#define RCAP 16          // staged nodes per thread: covers 256 nodes/graph
#define OFF1 12800000L
#define OFF2 51200000L

typedef float f32x4 __attribute__((ext_vector_type(4)));

// ---- graph start offsets (batch sorted; every graph id present) ----
__global__ void k_offsets(const int* __restrict__ b32, int* __restrict__ start) {
  int g = threadIdx.x;
  // int64 layout: odd int32 words are zero hi-words -> b32[NN-1] (odd index) == 0.
  bool is64 = (b32[NN - 1] == 0);
  if (g < NG) {
    int lo = 0, hi = NN;
    while (lo < hi) {
      int mid = (lo + hi) >> 1;
      int v = is64 ? b32[2 * mid] : b32[mid];
      if (v < g) lo = mid + 1; else hi = mid;
    }
    start[g] = lo;
  }
  if (g == 0) start[NG] = NN;
}

template<int STRIDE>
static __device__ __forceinline__ void body(
    const float* __restrict__ src, float* __restrict__ dst,
    int cbase, int gcomp0,
    const float* __restrict__ alpha, const float* __restrict__ beta,
    const float* __restrict__ gamma, int ns, int ne,
    float (*red)[16][8]) {
  int t  = threadIdx.x;
  int s  = t & 15;          // float4 slot within chunk (0..15)
  int ph = t >> 4;          // node phase (0..15)
  float invd = 1.0f / (float)(ne - ns);
  long coloff = (long)cbase + (s << 2);
  const float* p0 = src + (long)(ns + ph) * STRIDE + coloff;

  // ---- pass 1: staged loads + accumulate (compile-time stride) ----
  float s0=0,s1=0,s2=0,s3=0, q0=0,q1=0,q2=0,q3=0;
  f32x4 v[RCAP];
  #pragma unroll
  for (int i = 0; i < RCAP; ++i) {
    if (ns + ph + (i << 4) < ne) {
      f32x4 u = __builtin_nontemporal_load(
          reinterpret_cast<const f32x4*>(p0 + (long)i * 16 * STRIDE));
      v[i] = u;
      s0 += u.x; s1 += u.y; s2 += u.z; s3 += u.w;
      q0 += u.x*u.x; q1 += u.y*u.y; q2 += u.z*u.z; q3 += u.w*u.w;
    }
  }
  // overflow (graphs > 256 nodes): accumulate unstaged
  for (int n = ns + ph + (RCAP << 4); n < ne; n += 16) {
    f32x4 u = __builtin_nontemporal_load(
        reinterpret_cast<const f32x4*>(src + (long)n * STRIDE + coloff));
    s0 += u.x; s1 += u.y; s2 += u.z; s3 += u.w;
    q0 += u.x*u.x; q1 += u.y*u.y; q2 += u.z*u.z; q3 += u.w*u.w;
  }

  // ---- reduce over 16 phases: shfl ^16,^32 in-wave, LDS across 4 waves ----
  #define RED2(x) { x += __shfl_xor(x, 16); x += __shfl_xor(x, 32); }
  RED2(s0) RED2(s1) RED2(s2) RED2(s3) RED2(q0) RED2(q1) RED2(q2) RED2(q3)
  #undef RED2
  int w = t >> 6, l = t & 63;
  if (l < 16) {
    red[w][l][0]=s0; red[w][l][1]=s1; red[w][l][2]=s2; red[w][l][3]=s3;
    red[w][l][4]=q0; red[w][l][5]=q1; red[w][l][6]=q2; red[w][l][7]=q3;
  }
  __syncthreads();

  float S[4], Q[4];
  #pragma unroll
  for (int j = 0; j < 4; ++j) {
    S[j] = red[0][s][j]   + red[1][s][j]   + red[2][s][j]   + red[3][s][j];
    Q[j] = red[0][s][j+4] + red[1][s][j+4] + red[2][s][j+4] + red[3][s][j+4];
  }

  // ---- A = alpha*mean, B = gamma*rsqrt(var+eps), beta (way 0 only) ----
  float A[4], Bv[4], Be[4];
  #pragma unroll
  for (int j = 0; j < 4; ++j) {
    int c = gcomp0 + (s << 2) + j;
    int way, ch;
    if (c < 128)      { way = 0; ch = c; }
    else if (c < 512) { way = 1; ch = (c - 128) / 3; }
    else              { way = 2; ch = (c - 512) / 9; }
    float a  = alpha[way * NCH + ch];
    float gm = gamma[way * NCH + ch];
    float m  = S[j] * invd;
    float var = Q[j] * invd - m * m * a * (2.0f - a);  // E[(x - a*m)^2]
    A[j]  = m * a;
    Bv[j] = gm * rsqrtf(var + EPSV);
    Be[j] = (c < 128) ? beta[c] : 0.0f;
  }

  // ---- pass 2: apply from registers, nontemporal stores ----
  float* q0p = dst + (long)(ns + ph) * STRIDE + coloff;
  #pragma unroll
  for (int i = 0; i < RCAP; ++i) {
    if (ns + ph + (i << 4) < ne) {
      f32x4 u = v[i], o;
      o.x = (u.x - A[0]) * Bv[0] + Be[0];
      o.y = (u.y - A[1]) * Bv[1] + Be[1];
      o.z = (u.z - A[2]) * Bv[2] + Be[2];
      o.w = (u.w - A[3]) * Bv[3] + Be[3];
      __builtin_nontemporal_store(o,
          reinterpret_cast<f32x4*>(q0p + (long)i * 16 * STRIDE));
    }
  }
  for (int n = ns + ph + (RCAP << 4); n < ne; n += 16) {
    f32x4 u = __builtin_nontemporal_load(
        reinterpret_cast<const f32x4*>(src + (long)n * STRIDE + coloff));
    f32x4 o;
    o.x = (u.x - A[0]) * Bv[0] + Be[0];
    o.y = (u.y - A[1]) * Bv[1] + Be[1];
    o.z = (u.z - A[2]) * Bv[2] + Be[2];
    o.w = (u.w - A[3]) * Bv[3] + Be[3];
    __builtin_nontemporal_store(o,
        reinterpret_cast<f32x4*>(dst + (long)n * STRIDE + coloff));
  }
}

__global__ __launch_bounds__(NT) void k_fused(
    const float* __restrict__ x0, const float* __restrict__ x1,
    const float* __restrict__ x2, const float* __restrict__ alpha,
    const float* __restrict__ beta, const float* __restrict__ gamma,
    const int* __restrict__ start, float* __restrict__ out) {
  __shared__ float red[4][16][8];
  int bid = blockIdx.x;
  int g = bid / NCHUNK;
  int k = bid - g * NCHUNK;
  int ns = start[g], ne = start[g + 1];

  if (k < 2)
    body<128>(x0, out, k * 64, k * 64, alpha, beta, gamma, ns, ne, red);
  else if (k < 8)
    body<384>(x1, out + OFF1, (k - 2) * 64, 128 + (k - 2) * 64,
              alpha, beta, gamma, ns, ne, red);
  else
    body<1152>(x2, out + OFF2, (k - 8) * 64, 512 + (k - 8) * 64,
               alpha, beta, gamma, ns, ne, red);
}

extern "C" void kernel_launch(void* const* d_in, const int* in_sizes, int n_in,
                              void* d_out, int out_size, void* d_ws, size_t ws_size,
                              hipStream_t stream) {
  const float* x0    = (const float*)d_in[0];
  const float* x1    = (const float*)d_in[1];
  const float* x2    = (const float*)d_in[2];
  const float* alpha = (const float*)d_in[3];
  const float* beta  = (const float*)d_in[4];
  const float* gamma = (const float*)d_in[5];
  const int*   b32   = (const int*)d_in[6];   // batch: int32 or int64 (device-detected)
  float* out = (float*)d_out;

  int* start = (int*)d_ws;  // 513 ints

  k_offsets<<<1, 512, 0, stream>>>(b32, start);
  k_fused<<<NG * NCHUNK, NT, 0, stream>>>(x0, x1, x2, alpha, beta, gamma, start, out);
}

// Round 5
// 242.509 us; speedup vs baseline: 1.9955x; 1.0009x over previous
//
#include <hip/hip_runtime.h>

#define NN 100000
#define NG 512
#define NCH 128
#define EPSV 0.001f
#define NCHUNK 26        // 2 (x0) + 6 (x1) + 18 (x2) chunks of 16 float4 slots
#define NT 256
#define RCAP 16          // staged nodes per thread: covers 256 nodes/graph
#define OFF1 12800000L
#define OFF2 51200000L

typedef float f32x4 __attribute__((ext_vector_type(4)));

// ---- graph start offsets: parallel boundary scan over sorted batch ----
__global__ __launch_bounds__(NT) void k_offsets(const int* __restrict__ b32,
                                                int* __restrict__ start) {
  int i = blockIdx.x * NT + threadIdx.x;
  if (i >= NN) return;
  // int64 layout: odd int32 words are zero hi-words -> b32[NN-1] (odd idx) == 0.
  bool is64 = (b32[NN - 1] == 0);
  int cur  = is64 ? b32[2 * i] : b32[i];
  int prev = (i == 0) ? -1 : (is64 ? b32[2 * (i - 1)] : b32[i - 1]);
  for (int g = prev + 1; g <= cur; ++g) start[g] = i;  // ≤1 iter when all ids present
  if (i == 0) start[NG] = NN;
}

template<int STRIDE>
static __device__ __forceinline__ void body(
    const float* __restrict__ src, float* __restrict__ dst,
    int cbase, int gcomp0,
    const float* __restrict__ alpha, const float* __restrict__ beta,
    const float* __restrict__ gamma, int ns, int ne,
    float (*red)[16][8]) {
  int t  = threadIdx.x;
  int s  = t & 15;          // float4 slot within chunk (0..15)
  int ph = t >> 4;          // node phase (0..15)
  float invd = 1.0f / (float)(ne - ns);
  long coloff = (long)cbase + (s << 2);
  const float* p0 = src + (long)(ns + ph) * STRIDE + coloff;

  // ---- pass 1: staged loads + accumulate (compile-time stride) ----
  float s0=0,s1=0,s2=0,s3=0, q0=0,q1=0,q2=0,q3=0;
  f32x4 v[RCAP];
  #pragma unroll
  for (int i = 0; i < RCAP; ++i) {
    if (ns + ph + (i << 4) < ne) {
      f32x4 u = __builtin_nontemporal_load(
          reinterpret_cast<const f32x4*>(p0 + (long)i * 16 * STRIDE));
      v[i] = u;
      s0 += u.x; s1 += u.y; s2 += u.z; s3 += u.w;
      q0 += u.x*u.x; q1 += u.y*u.y; q2 += u.z*u.z; q3 += u.w*u.w;
    }
  }
  // overflow (graphs > 256 nodes): accumulate unstaged
  for (int n = ns + ph + (RCAP << 4); n < ne; n += 16) {
    f32x4 u = __builtin_nontemporal_load(
        reinterpret_cast<const f32x4*>(src + (long)n * STRIDE + coloff));
    s0 += u.x; s1 += u.y; s2 += u.z; s3 += u.w;
    q0 += u.x*u.x; q1 += u.y*u.y; q2 += u.z*u.z; q3 += u.w*u.w;
  }

  // ---- reduce over 16 phases: shfl ^16,^32 in-wave, LDS across 4 waves ----
  #define RED2(x) { x += __shfl_xor(x, 16); x += __shfl_xor(x, 32); }
  RED2(s0) RED2(s1) RED2(s2) RED2(s3) RED2(q0) RED2(q1) RED2(q2) RED2(q3)
  #undef RED2
  int w = t >> 6, l = t & 63;
  if (l < 16) {
    red[w][l][0]=s0; red[w][l][1]=s1; red[w][l][2]=s2; red[w][l][3]=s3;
    red[w][l][4]=q0; red[w][l][5]=q1; red[w][l][6]=q2; red[w][l][7]=q3;
  }
  __syncthreads();

  float S[4], Q[4];
  #pragma unroll
  for (int j = 0; j < 4; ++j) {
    S[j] = red[0][s][j]   + red[1][s][j]   + red[2][s][j]   + red[3][s][j];
    Q[j] = red[0][s][j+4] + red[1][s][j+4] + red[2][s][j+4] + red[3][s][j+4];
  }

  // ---- A = alpha*mean, B = gamma*rsqrt(var+eps), beta (way 0 only) ----
  float A[4], Bv[4], Be[4];
  #pragma unroll
  for (int j = 0; j < 4; ++j) {
    int c = gcomp0 + (s << 2) + j;
    int way, ch;
    if (c < 128)      { way = 0; ch = c; }
    else if (c < 512) { way = 1; ch = (c - 128) / 3; }
    else              { way = 2; ch = (c - 512) / 9; }
    float a  = alpha[way * NCH + ch];
    float gm = gamma[way * NCH + ch];
    float m  = S[j] * invd;
    float var = Q[j] * invd - m * m * a * (2.0f - a);  // E[(x - a*m)^2]
    A[j]  = m * a;
    Bv[j] = gm * rsqrtf(var + EPSV);
    Be[j] = (c < 128) ? beta[c] : 0.0f;
  }

  // ---- pass 2: apply from registers, nontemporal stores ----
  float* q0p = dst + (long)(ns + ph) * STRIDE + coloff;
  #pragma unroll
  for (int i = 0; i < RCAP; ++i) {
    if (ns + ph + (i << 4) < ne) {
      f32x4 u = v[i], o;
      o.x = (u.x - A[0]) * Bv[0] + Be[0];
      o.y = (u.y - A[1]) * Bv[1] + Be[1];
      o.z = (u.z - A[2]) * Bv[2] + Be[2];
      o.w = (u.w - A[3]) * Bv[3] + Be[3];
      __builtin_nontemporal_store(o,
          reinterpret_cast<f32x4*>(q0p + (long)i * 16 * STRIDE));
    }
  }
  for (int n = ns + ph + (RCAP << 4); n < ne; n += 16) {
    f32x4 u = __builtin_nontemporal_load(
        reinterpret_cast<const f32x4*>(src + (long)n * STRIDE + coloff));
    f32x4 o;
    o.x = (u.x - A[0]) * Bv[0] + Be[0];
    o.y = (u.y - A[1]) * Bv[1] + Be[1];
    o.z = (u.z - A[2]) * Bv[2] + Be[2];
    o.w = (u.w - A[3]) * Bv[3] + Be[3];
    __builtin_nontemporal_store(o,
        reinterpret_cast<f32x4*>(dst + (long)n * STRIDE + coloff));
  }
}

__global__ __launch_bounds__(NT) void k_fused(
    const float* __restrict__ x0, const float* __restrict__ x1,
    const float* __restrict__ x2, const float* __restrict__ alpha,
    const float* __restrict__ beta, const float* __restrict__ gamma,
    const int* __restrict__ start, float* __restrict__ out) {
  __shared__ float red[4][16][8];
  int bid = blockIdx.x;
  int g = bid / NCHUNK;
  int k = bid - g * NCHUNK;
  int ns = start[g], ne = start[g + 1];

  if (k < 2)
    body<128>(x0, out, k * 64, k * 64, alpha, beta, gamma, ns, ne, red);
  else if (k < 8)
    body<384>(x1, out + OFF1, (k - 2) * 64, 128 + (k - 2) * 64,
              alpha, beta, gamma, ns, ne, red);
  else
    body<1152>(x2, out + OFF2, (k - 8) * 64, 512 + (k - 8) * 64,
               alpha, beta, gamma, ns, ne, red);
}

extern "C" void kernel_launch(void* const* d_in, const int* in_sizes, int n_in,
                              void* d_out, int out_size, void* d_ws, size_t ws_size,
                              hipStream_t stream) {
  const float* x0    = (const float*)d_in[0];
  const float* x1    = (const float*)d_in[1];
  const float* x2    = (const float*)d_in[2];
  const float* alpha = (const float*)d_in[3];
  const float* beta  = (const float*)d_in[4];
  const float* gamma = (const float*)d_in[5];
  const int*   b32   = (const int*)d_in[6];   // batch: int32 or int64 (device-detected)
  float* out = (float*)d_out;

  int* start = (int*)d_ws;  // 513 ints

  k_offsets<<<(NN + NT - 1) / NT, NT, 0, stream>>>(b32, start);
  k_fused<<<NG * NCHUNK, NT, 0, stream>>>(x0, x1, x2, alpha, beta, gamma, start, out);
}